// Round 8
// baseline (141.278 us; speedup 1.0000x reference)
//
#include <hip/hip_runtime.h>
#include <hip/hip_cooperative_groups.h>
#include <math.h>

namespace cg = cooperative_groups;

// Retention via chunked linear attention.
// PRIMARY: single cooperative megakernel (105.8 KB LDS, 1 block/CU, 256 blocks).
// FALLBACK (if cooperative launch is rejected): round-5 5-kernel pipeline.

constexpr int B = 8, S = 2048, D = 128;
constexpr int C = 64, NC = S / C;      // 32 chunks/batch
constexpr int BS = B * S;
constexpr int NCH = B * NC;            // 256 chunks == 256 blocks == #CUs
#define GAMMA_F 0.9865f

typedef __attribute__((ext_vector_type(8))) short short8;
typedef __attribute__((ext_vector_type(8))) unsigned short ushort8;
typedef __attribute__((ext_vector_type(4))) float f32x4;

__device__ inline unsigned short f2bf(float f) {
  unsigned u = __builtin_bit_cast(unsigned, f);
  return (unsigned short)((u + 0x7FFF + ((u >> 16) & 1)) >> 16);   // RNE
}
__device__ inline float bf2f(unsigned short h) {
  return __builtin_bit_cast(float, (unsigned)h << 16);
}

// ===================== PRIMARY: cooperative megakernel =====================
__global__ __launch_bounds__(256, 1) void k_fused(
    const float* __restrict__ xq, const float* __restrict__ xk,
    const float* __restrict__ xv, const float* __restrict__ W,
    float* __restrict__ cs, unsigned short* __restrict__ Hc,
    unsigned short* __restrict__ HS, float* __restrict__ out) {
  // LDS 105.75 KB. ovl holds wt[128][136] during P1; kT[128][72]+al[64][72] after.
  __shared__ unsigned short qkv[3][64][136];        // 52.2 KB  Q',K'',V(->V')
  __shared__ alignas(16) char ovl[34816];           // 34.8 KB  overlay
  __shared__ unsigned short vT[128][72];            // 18.4 KB  V'^T (m-fast)
  __shared__ float csp[128];
  __shared__ float invl[64];
  __shared__ float css[4][128];
  auto wt = (unsigned short(*)[136])ovl;            // P1 only
  auto kT = (unsigned short(*)[72])ovl;             // P2 (after grid.sync #1)
  auto al = (unsigned short(*)[72])(ovl + 18432);   // P2..P4

  cg::grid_group grid = cg::this_grid();
  int bc = blockIdx.x, b = bc >> 5, c = bc & 31;
  int tid = threadIdx.x, w = tid >> 6, lane = tid & 63;
  int l15 = lane & 15;
  int kg = (lane >> 4) * 8;
  int arow = w * 16 + l15;               // local A-operand row
  int crow = w * 16 + (lane >> 4) * 4;   // local C-row base

  // ================= P1: wt build (LDS) + projections into LDS =================
  for (int idx = tid; idx < 128 * 128; idx += 256) {
    int cc = idx >> 7, k = idx & 127;       // consecutive lanes -> consecutive k:
    wt[cc][k] = f2bf(W[k * 128 + cc]);      // conflict-free LDS writes
  }
  float lgf = logf(GAMMA_F);
  __syncthreads();

  for (int mat = 0; mat < 3; mat++) {
    const float* X = (mat == 0) ? xq : ((mat == 1) ? xk : xv);
    f32x4 acc[8];
#pragma unroll
    for (int j = 0; j < 8; j++) acc[j] = (f32x4){0.f, 0.f, 0.f, 0.f};
#pragma unroll
    for (int t = 0; t < 4; t++) {
      int k0 = t * 32 + kg;
      const float* ap = X + (size_t)(bc * 64 + arow) * 128 + k0;
      float a8[8];
      *(f32x4*)(a8) = *(const f32x4*)ap;
      *(f32x4*)(a8 + 4) = *(const f32x4*)(ap + 4);
      short8 af;
#pragma unroll
      for (int i = 0; i < 8; i++) af[i] = (short)f2bf(a8[i]);
#pragma unroll
      for (int j = 0; j < 8; j++) {
        short8 bf = *(const short8*)&wt[j * 16 + l15][k0];
        acc[j] = __builtin_amdgcn_mfma_f32_16x16x32_bf16(af, bf, acc[j], 0, 0, 0);
      }
    }
    float cacc[8];
#pragma unroll
    for (int j = 0; j < 8; j++) cacc[j] = 0.f;
#pragma unroll
    for (int rr = 0; rr < 4; rr++) {
      int row = crow + rr;
      int n = (bc * 64 + row) & (S - 1);
      float sc;
      if (mat == 0) {
        sc = expf(-lgf * (float)n) * 0.088388347f;          // gamma^-n / sqrt(128)
      } else if (mat == 1) {
        float rs = (expf(-lgf * (float)(n + 1)) - 1.f) * (GAMMA_F / (1.f - GAMMA_F));
        sc = expf(lgf * (float)n) / sqrtf(rs);              // gamma^n / sqrt(rowsum)
      } else {
        sc = 1.f;
      }
#pragma unroll
      for (int j = 0; j < 8; j++) {
        float v = acc[j][rr] * sc;
        qkv[mat][row][j * 16 + l15] = f2bf(v);
        if (mat == 1) cacc[j] += v;
      }
    }
    if (mat == 1) {   // K'' column sums -> cs[bc] (f32)
#pragma unroll
      for (int j = 0; j < 8; j++) {
        cacc[j] += __shfl_xor(cacc[j], 16);
        cacc[j] += __shfl_xor(cacc[j], 32);
      }
      if ((lane >> 4) == 0)
#pragma unroll
        for (int j = 0; j < 8; j++) css[w][j * 16 + lane] = cacc[j];
      __syncthreads();
      if (tid < 128)
        cs[(size_t)bc * 128 + tid] = css[0][tid] + css[1][tid] + css[2][tid] + css[3][tid];
    }
  }
  grid.sync();   // #1 — cs visible device-wide; wt dead, ovl becomes kT+al

  // ================= P2: A-tile, s, V', transposes, Hc =================
  if (tid < 128) {
    float a = 0.f;
    for (int cc = 0; cc < c; cc++) a += cs[(size_t)(b * NC + cc) * 128 + tid];
    csp[tid] = a;
  }
  // A = tril(Q' K''^T)
  f32x4 a1[4];
#pragma unroll
  for (int m = 0; m < 4; m++) a1[m] = (f32x4){0.f, 0.f, 0.f, 0.f};
#pragma unroll
  for (int t = 0; t < 4; t++) {
    int k0 = t * 32 + kg;
    short8 af = *(const short8*)&qkv[0][arow][k0];
#pragma unroll
    for (int mt = 0; mt < 4; mt++) {
      short8 bf = *(const short8*)&qkv[1][mt * 16 + l15][k0];
      a1[mt] = __builtin_amdgcn_mfma_f32_16x16x32_bf16(af, bf, a1[mt], 0, 0, 0);
    }
  }
  float rsum[4] = {0.f, 0.f, 0.f, 0.f};
#pragma unroll
  for (int mt = 0; mt < 4; mt++)
#pragma unroll
    for (int rr = 0; rr < 4; rr++) {
      int n_l = crow + rr, m_l = mt * 16 + l15;
      float mv = (n_l >= m_l) ? a1[mt][rr] : 0.f;
      al[n_l][m_l] = f2bf(mv);
      rsum[rr] += mv;
    }
#pragma unroll
  for (int rr = 0; rr < 4; rr++) {
    float r = rsum[rr];
    r += __shfl_xor(r, 1); r += __shfl_xor(r, 2);
    r += __shfl_xor(r, 4); r += __shfl_xor(r, 8);
    rsum[rr] = r;
  }
  __syncthreads();   // csp, al visible
  // s = rowsum(A) + Q'.csp ; invl = 1/max(|s|,1)
#pragma unroll
  for (int rr = 0; rr < 4; rr++) {
    int row = crow + rr;
    ushort8 q8 = *(const ushort8*)&qkv[0][row][l15 * 8];
    float dt = 0.f;
#pragma unroll
    for (int ii = 0; ii < 8; ii++) dt += bf2f(q8[ii]) * csp[l15 * 8 + ii];
    dt += __shfl_xor(dt, 1); dt += __shfl_xor(dt, 2);
    dt += __shfl_xor(dt, 4); dt += __shfl_xor(dt, 8);
    if (l15 == 0) invl[row] = 1.f / fmaxf(fabsf(rsum[rr] + dt), 1.f);
  }
  // kT pack (reads qkv[1], stable)
  {
    int d = tid & 127, mh = tid >> 7;
#pragma unroll
    for (int mg = 0; mg < 4; mg++) {
      ushort8 pk;
#pragma unroll
      for (int i = 0; i < 8; i++) pk[i] = qkv[1][mh * 32 + mg * 8 + i][d];
      *(ushort8*)&kT[d][mh * 32 + mg * 8] = pk;
    }
  }
  __syncthreads();   // invl, kT visible
  // V' = V * invl, in place
#pragma unroll
  for (int i = 0; i < 4; i++) {
    int e = (i * 256 + tid) * 8;
    int row = e >> 7, col = e & 127;
    ushort8 v8 = *(const ushort8*)&qkv[2][row][col];
    float inv = invl[row];
    ushort8 o;
#pragma unroll
    for (int ii = 0; ii < 8; ii++) o[ii] = f2bf(bf2f(v8[ii]) * inv);
    *(ushort8*)&qkv[2][row][col] = o;
  }
  __syncthreads();
  // vT pack
  {
    int d = tid & 127, mh = tid >> 7;
#pragma unroll
    for (int mg = 0; mg < 4; mg++) {
      ushort8 pk;
#pragma unroll
      for (int i = 0; i < 8; i++) pk[i] = qkv[2][mh * 32 + mg * 8 + i][d];
      *(ushort8*)&vT[d][mh * 32 + mg * 8] = pk;
    }
  }
  __syncthreads();
  // Hc[d2][d1] = sum_m V'[m][d2] K''[m][d1]
  {
    f32x4 hacc[2][8];
#pragma unroll
    for (int i = 0; i < 2; i++)
#pragma unroll
      for (int j = 0; j < 8; j++) hacc[i][j] = (f32x4){0.f, 0.f, 0.f, 0.f};
#pragma unroll
    for (int t = 0; t < 2; t++) {
      int k0 = t * 32 + kg;
      short8 a2[2];
#pragma unroll
      for (int i = 0; i < 2; i++)
        a2[i] = *(const short8*)&vT[w * 32 + i * 16 + l15][k0];
#pragma unroll
      for (int j = 0; j < 8; j++) {
        short8 bf = *(const short8*)&kT[j * 16 + l15][k0];
#pragma unroll
        for (int i = 0; i < 2; i++)
          hacc[i][j] = __builtin_amdgcn_mfma_f32_16x16x32_bf16(a2[i], bf, hacc[i][j], 0, 0, 0);
      }
    }
    unsigned short* g = Hc + (size_t)bc * D * D;
#pragma unroll
    for (int i = 0; i < 2; i++)
#pragma unroll
      for (int j = 0; j < 8; j++)
#pragma unroll
        for (int rr = 0; rr < 4; rr++)
          g[(size_t)(w * 32 + i * 16 + (lane >> 4) * 4 + rr) * D + j * 16 + l15] =
              f2bf(hacc[i][j][rr]);
  }
  grid.sync();   // #2 — Hc visible

  // ================= P3: HS = exclusive chunk prefix of Hc =================
  {
    int d2 = c * 4 + (tid >> 6);
    int s16 = tid & 63;
    if (s16 < 16) {
      int d1 = s16 * 8;
      size_t off = ((size_t)(b * NC) * D + d2) * D + d1;
      ushort8 v[NC];
#pragma unroll
      for (int c2 = 0; c2 < NC; c2++)
        v[c2] = *(const ushort8*)(Hc + off + (size_t)c2 * D * D);
      float run[8];
#pragma unroll
      for (int j = 0; j < 8; j++) run[j] = 0.f;
#pragma unroll
      for (int c2 = 0; c2 < NC; c2++) {
        ushort8 o;
#pragma unroll
        for (int j = 0; j < 8; j++) {
          o[j] = f2bf(run[j]);
          run[j] += bf2f(v[c2][j]);
        }
        *(ushort8*)(HS + off + (size_t)c2 * D * D) = o;
      }
    }
  }
  grid.sync();   // #3 — HS visible

  // ================= P4: out = Q'@SE + A@V' =================
  {
    f32x4 oacc[8];
#pragma unroll
    for (int j = 0; j < 8; j++) oacc[j] = (f32x4){0.f, 0.f, 0.f, 0.f};
    const unsigned short* hrow = HS + (size_t)bc * D * D;
#pragma unroll
    for (int t = 0; t < 4; t++) {
      int k0 = t * 32 + kg;
      short8 af = *(const short8*)&qkv[0][arow][k0];
#pragma unroll
      for (int j = 0; j < 8; j++) {
        short8 bf = *(const short8*)(hrow + (size_t)(j * 16 + l15) * D + k0);
        oacc[j] = __builtin_amdgcn_mfma_f32_16x16x32_bf16(af, bf, oacc[j], 0, 0, 0);
      }
    }
#pragma unroll
    for (int t = 0; t < 2; t++) {
      int k0 = t * 32 + kg;
      short8 af = *(const short8*)&al[arow][k0];
#pragma unroll
      for (int j = 0; j < 8; j++) {
        short8 bf = *(const short8*)&vT[j * 16 + l15][k0];
        oacc[j] = __builtin_amdgcn_mfma_f32_16x16x32_bf16(af, bf, oacc[j], 0, 0, 0);
      }
    }
    size_t base = (size_t)bc * C * D;
#pragma unroll
    for (int j = 0; j < 8; j++)
#pragma unroll
      for (int rr = 0; rr < 4; rr++)
        out[base + (size_t)(crow + rr) * D + j * 16 + l15] = oacc[j][rr];
  }
}

// ===================== FALLBACK: round-5 verified pipeline =====================
__global__ void fb_init(const float* __restrict__ W, unsigned short* __restrict__ wt,
                        float* __restrict__ qs, float* __restrict__ ks) {
  int bid = blockIdx.x, tid = threadIdx.x;
  if (bid < 64) {
    int idx = bid * 256 + tid;
    int k = idx & 127, c = idx >> 7;
    wt[c * 128 + k] = f2bf(W[k * 128 + c]);
  } else {
    int n = (bid - 64) * 256 + tid;
    if (n < S) {
      double g = (double)GAMMA_F;
      double lg = log(g);
      double gmn = exp(-lg * (double)n);
      double gn  = exp(lg * (double)n);
      double ginv = 1.0 / g;
      double rs = (exp(log(ginv) * (double)(n + 1)) - 1.0) / (ginv - 1.0);
      qs[n] = (float)(gmn / sqrt(128.0));
      ks[n] = (float)(gn / sqrt(rs));
    }
  }
}

__global__ __launch_bounds__(256) void fb_proj(
    const float* __restrict__ xq, const float* __restrict__ xk,
    const float* __restrict__ xv, const unsigned short* __restrict__ wt,
    const float* __restrict__ qs, const float* __restrict__ ks,
    unsigned short* __restrict__ qb, unsigned short* __restrict__ kb,
    unsigned short* __restrict__ vb, float* __restrict__ cs) {
  __shared__ float css[4][128];
  int mat = blockIdx.y;
  const float* X = (mat == 0) ? xq : ((mat == 1) ? xk : xv);
  unsigned short* Ob = (mat == 0) ? qb : ((mat == 1) ? kb : vb);

  int tid = threadIdx.x, w = tid >> 6, lane = tid & 63;
  int bc = blockIdx.x;
  int r0 = bc * 64 + w * 16;
  int arow = r0 + (lane & 15);
  int kg = (lane >> 4) * 8;

  f32x4 acc[8];
#pragma unroll
  for (int j = 0; j < 8; j++) acc[j] = (f32x4){0.f, 0.f, 0.f, 0.f};
#pragma unroll
  for (int t = 0; t < 4; t++) {
    int k0 = t * 32 + kg;
    const float* ap = X + (size_t)arow * 128 + k0;
    float a8[8];
    *(f32x4*)(a8) = *(const f32x4*)ap;
    *(f32x4*)(a8 + 4) = *(const f32x4*)(ap + 4);
    short8 af;
#pragma unroll
    for (int i = 0; i < 8; i++) af[i] = (short)f2bf(a8[i]);
#pragma unroll
    for (int j = 0; j < 8; j++) {
      short8 bf = *(const short8*)(wt + (size_t)(j * 16 + (lane & 15)) * 128 + k0);
      acc[j] = __builtin_amdgcn_mfma_f32_16x16x32_bf16(af, bf, acc[j], 0, 0, 0);
    }
  }
  int crow = r0 + (lane >> 4) * 4;
  float csp[8];
#pragma unroll
  for (int j = 0; j < 8; j++) csp[j] = 0.f;
#pragma unroll
  for (int rr = 0; rr < 4; rr++) {
    int row = crow + rr;
    int n = row & (S - 1);
    float sc = (mat == 0) ? qs[n] : ((mat == 1) ? ks[n] : 1.0f);
#pragma unroll
    for (int j = 0; j < 8; j++) {
      float v = acc[j][rr] * sc;
      Ob[(size_t)row * 128 + j * 16 + (lane & 15)] = f2bf(v);
      csp[j] += v;
    }
  }
  if (mat == 1) {
#pragma unroll
    for (int j = 0; j < 8; j++) {
      csp[j] += __shfl_xor(csp[j], 16);
      csp[j] += __shfl_xor(csp[j], 32);
    }
    if ((lane >> 4) == 0)
#pragma unroll
      for (int j = 0; j < 8; j++) css[w][j * 16 + lane] = csp[j];
  }
  __syncthreads();
  if (mat == 1 && tid < 128)
    cs[bc * 128 + tid] = css[0][tid] + css[1][tid] + css[2][tid] + css[3][tid];
}

__global__ __launch_bounds__(256) void fb_mid(
    const unsigned short* __restrict__ qb, const unsigned short* __restrict__ kb,
    const unsigned short* __restrict__ vb, const float* __restrict__ cs,
    unsigned short* __restrict__ al, unsigned short* __restrict__ vbT,
    unsigned short* __restrict__ Hc) {
  __shared__ unsigned short kraw[64][136];
  __shared__ unsigned short kT[128][72];
  __shared__ unsigned short vT[128][72];
  __shared__ float csp[128];
  __shared__ float invl[64];
  int bc = blockIdx.x, b = bc >> 5, c = bc & 31;
  int tid = threadIdx.x, w = tid >> 6, lane = tid & 63;
  size_t base = (size_t)bc * C * D;
  int kg = (lane >> 4) * 8;
  int arow = w * 16 + (lane & 15);
  int crow = w * 16 + (lane >> 4) * 4;

  if (tid < 128) {
    float a = 0.f;
    for (int cc = 0; cc < c; cc++) a += cs[(size_t)(b * NC + cc) * 128 + tid];
    csp[tid] = a;
  }
  f32x4 a1[4];
#pragma unroll
  for (int m = 0; m < 4; m++) a1[m] = (f32x4){0.f, 0.f, 0.f, 0.f};
#pragma unroll
  for (int t = 0; t < 4; t++) {
    int k0 = t * 32 + kg;
    short8 af = *(const short8*)(qb + base + (size_t)arow * D + k0);
#pragma unroll
    for (int mt = 0; mt < 4; mt++) {
      short8 bf = *(const short8*)(kb + base + (size_t)(mt * 16 + (lane & 15)) * D + k0);
      a1[mt] = __builtin_amdgcn_mfma_f32_16x16x32_bf16(af, bf, a1[mt], 0, 0, 0);
    }
  }
  unsigned short* alg = al + (size_t)bc * 64 * 64;
  float rsum[4] = {0.f, 0.f, 0.f, 0.f};
#pragma unroll
  for (int mt = 0; mt < 4; mt++)
#pragma unroll
    for (int rr = 0; rr < 4; rr++) {
      int n_l = crow + rr, m_l = mt * 16 + (lane & 15);
      float mv = (n_l >= m_l) ? a1[mt][rr] : 0.f;
      alg[n_l * 64 + m_l] = f2bf(mv);
      rsum[rr] += mv;
    }
#pragma unroll
  for (int rr = 0; rr < 4; rr++) {
    float r = rsum[rr];
    r += __shfl_xor(r, 1); r += __shfl_xor(r, 2);
    r += __shfl_xor(r, 4); r += __shfl_xor(r, 8);
    rsum[rr] = r;
  }
  __syncthreads();
#pragma unroll
  for (int rr = 0; rr < 4; rr++) {
    int row = crow + rr;
    ushort8 q8 = *(const ushort8*)(qb + base + (size_t)row * D + (lane & 15) * 8);
    float dt = 0.f;
#pragma unroll
    for (int ii = 0; ii < 8; ii++) dt += bf2f(q8[ii]) * csp[(lane & 15) * 8 + ii];
    dt += __shfl_xor(dt, 1); dt += __shfl_xor(dt, 2);
    dt += __shfl_xor(dt, 4); dt += __shfl_xor(dt, 8);
    if ((lane & 15) == 0) invl[row] = 1.f / fmaxf(fabsf(rsum[rr] + dt), 1.f);
  }
#pragma unroll
  for (int i = 0; i < 4; i++) {
    int e = (i * 256 + tid) * 8;
    *(ushort8*)&kraw[e >> 7][e & 127] = *(const ushort8*)(kb + base + e);
  }
  __syncthreads();
  {
    int d = tid & 127, mh = tid >> 7;
#pragma unroll
    for (int mg = 0; mg < 4; mg++) {
      ushort8 pk;
#pragma unroll
      for (int i = 0; i < 8; i++) pk[i] = kraw[mh * 32 + mg * 8 + i][d];
      *(ushort8*)&kT[d][mh * 32 + mg * 8] = pk;
    }
  }
  __syncthreads();
#pragma unroll
  for (int i = 0; i < 4; i++) {
    int e = (i * 256 + tid) * 8;
    int row = e >> 7, col = e & 127;
    ushort8 v8 = *(const ushort8*)(vb + base + e);
    float inv = invl[row];
    ushort8 o;
#pragma unroll
    for (int ii = 0; ii < 8; ii++) o[ii] = f2bf(bf2f(v8[ii]) * inv);
    *(ushort8*)&kraw[row][col] = o;
  }
  __syncthreads();
  {
    int d = tid & 127, mh = tid >> 7;
#pragma unroll
    for (int mg = 0; mg < 4; mg++) {
      ushort8 pk;
#pragma unroll
      for (int i = 0; i < 8; i++) pk[i] = kraw[mh * 32 + mg * 8 + i][d];
      *(ushort8*)&vT[d][mh * 32 + mg * 8] = pk;
    }
  }
  __syncthreads();
  f32x4 acc[2][8];
#pragma unroll
  for (int i = 0; i < 2; i++)
#pragma unroll
    for (int j = 0; j < 8; j++) acc[i][j] = (f32x4){0.f, 0.f, 0.f, 0.f};
#pragma unroll
  for (int t = 0; t < 2; t++) {
    int k0 = t * 32 + kg;
    short8 a2[2];
#pragma unroll
    for (int i = 0; i < 2; i++)
      a2[i] = *(const short8*)&vT[w * 32 + i * 16 + (lane & 15)][k0];
#pragma unroll
    for (int j = 0; j < 8; j++) {
      short8 bf = *(const short8*)&kT[j * 16 + (lane & 15)][k0];
#pragma unroll
      for (int i = 0; i < 2; i++)
        acc[i][j] = __builtin_amdgcn_mfma_f32_16x16x32_bf16(a2[i], bf, acc[i][j], 0, 0, 0);
    }
  }
  unsigned short* g = Hc + (size_t)bc * D * D;
#pragma unroll
  for (int i = 0; i < 2; i++)
#pragma unroll
    for (int j = 0; j < 8; j++)
#pragma unroll
      for (int rr = 0; rr < 4; rr++)
        g[(size_t)(w * 32 + i * 16 + (lane >> 4) * 4 + rr) * D + j * 16 + (lane & 15)] =
            f2bf(acc[i][j][rr]);
  {
    int d = tid >> 1, pp = (tid & 1) * 32;
    unsigned short* dst = vbT + (size_t)bc * D * C + (size_t)d * C + pp;
#pragma unroll
    for (int q8i = 0; q8i < 4; q8i++)
      *(ushort8*)(dst + q8i * 8) = *(ushort8*)&vT[d][pp + q8i * 8];
  }
}

__global__ __launch_bounds__(64) void fb_gscan(const unsigned short* __restrict__ Hc,
                                               unsigned short* __restrict__ HS) {
  int b = blockIdx.x, gy = blockIdx.y, t = threadIdx.x;
  int d2 = gy * 4 + (t >> 4), d1 = (t & 15) * 8;
  size_t off = ((size_t)(b * NC) * D + d2) * D + d1;
  ushort8 v[NC];
#pragma unroll
  for (int c = 0; c < NC; c++)
    v[c] = *(const ushort8*)(Hc + off + (size_t)c * D * D);
  float run[8];
#pragma unroll
  for (int j = 0; j < 8; j++) run[j] = 0.f;
#pragma unroll
  for (int c = 0; c < NC; c++) {
    ushort8 o;
#pragma unroll
    for (int j = 0; j < 8; j++) {
      o[j] = f2bf(run[j]);
      run[j] += bf2f(v[c][j]);
    }
    *(ushort8*)(HS + off + (size_t)c * D * D) = o;
  }
}

__global__ __launch_bounds__(256) void fb_out(
    const unsigned short* __restrict__ qb, const unsigned short* __restrict__ al,
    const unsigned short* __restrict__ vbT, const unsigned short* __restrict__ HS,
    float* __restrict__ out) {
  int bc = blockIdx.x, tid = threadIdx.x, w = tid >> 6, lane = tid & 63;
  size_t base = (size_t)bc * C * D;
  int kg = (lane >> 4) * 8;
  int arow = w * 16 + (lane & 15);
  int crow = w * 16 + (lane >> 4) * 4;

  f32x4 acc[8];
#pragma unroll
  for (int j = 0; j < 8; j++) acc[j] = (f32x4){0.f, 0.f, 0.f, 0.f};
  const unsigned short* hrow = HS + (size_t)bc * D * D;
#pragma unroll
  for (int t = 0; t < 4; t++) {
    int k0 = t * 32 + kg;
    short8 af = *(const short8*)(qb + base + (size_t)arow * D + k0);
#pragma unroll
    for (int j = 0; j < 8; j++) {
      short8 bf = *(const short8*)(hrow + (size_t)(j * 16 + (lane & 15)) * D + k0);
      acc[j] = __builtin_amdgcn_mfma_f32_16x16x32_bf16(af, bf, acc[j], 0, 0, 0);
    }
  }
  const unsigned short* alg = al + (size_t)bc * 64 * 64;
  const unsigned short* vt = vbT + (size_t)bc * D * C;
#pragma unroll
  for (int t = 0; t < 2; t++) {
    int k0 = t * 32 + kg;
    short8 af = *(const short8*)(alg + (size_t)arow * 64 + k0);
#pragma unroll
    for (int j = 0; j < 8; j++) {
      short8 bf = *(const short8*)(vt + (size_t)(j * 16 + (lane & 15)) * C + k0);
      acc[j] = __builtin_amdgcn_mfma_f32_16x16x32_bf16(af, bf, acc[j], 0, 0, 0);
    }
  }
#pragma unroll
  for (int j = 0; j < 8; j++)
#pragma unroll
    for (int rr = 0; rr < 4; rr++)
      out[base + (size_t)(crow + rr) * D + j * 16 + (lane & 15)] = acc[j][rr];
}

extern "C" void kernel_launch(void* const* d_in, const int* in_sizes, int n_in,
                              void* d_out, int out_size, void* d_ws, size_t ws_size,
                              hipStream_t stream) {
  const float* xq = (const float*)d_in[0];
  const float* xk = (const float*)d_in[1];
  const float* xv = (const float*)d_in[2];
  const float* W  = (const float*)d_in[3];
  float* out = (float*)d_out;

  char* p = (char*)d_ws;
  // megakernel region
  float* cs_m = (float*)p;                   p += (size_t)NCH * D * 4;
  unsigned short* Hc_m = (unsigned short*)p; p += (size_t)NCH * D * D * 2;
  unsigned short* HS_m = (unsigned short*)p; p += (size_t)NCH * D * D * 2;
  // fallback region (disjoint)
  unsigned short* qb  = (unsigned short*)p;  p += (size_t)BS * D * 2;
  unsigned short* kb  = (unsigned short*)p;  p += (size_t)BS * D * 2;
  unsigned short* vb  = (unsigned short*)p;  p += (size_t)BS * D * 2;
  unsigned short* vbT = (unsigned short*)p;  p += (size_t)NCH * D * C * 2;
  unsigned short* alg = (unsigned short*)p;  p += (size_t)NCH * C * C * 2;
  unsigned short* Hc  = (unsigned short*)p;  p += (size_t)NCH * D * D * 2;
  unsigned short* HS  = (unsigned short*)p;  p += (size_t)NCH * D * D * 2;
  unsigned short* wt  = (unsigned short*)p;  p += (size_t)D * D * 2;
  float* cs = (float*)p;                     p += (size_t)NCH * D * 4;
  float* qs = (float*)p;                     p += (size_t)S * 4;
  float* ks = (float*)p;                     p += (size_t)S * 4;

  void* args[] = {(void*)&xq, (void*)&xk, (void*)&xv, (void*)&W,
                  (void*)&cs_m, (void*)&Hc_m, (void*)&HS_m, (void*)&out};
  hipError_t e = hipLaunchCooperativeKernel((const void*)k_fused, dim3(NCH),
                                            dim3(256), args, 0, stream);
  if (e != hipSuccess) {
    // fallback: verified round-5 pipeline
    hipLaunchKernelGGL(fb_init, dim3(72), dim3(256), 0, stream, W, wt, qs, ks);
    hipLaunchKernelGGL(fb_proj, dim3(NCH, 3), dim3(256), 0, stream,
                       xq, xk, xv, wt, qs, ks, qb, kb, vb, cs);
    hipLaunchKernelGGL(fb_mid, dim3(NCH), dim3(256), 0, stream, qb, kb, vb, cs,
                       alg, vbT, Hc);
    hipLaunchKernelGGL(fb_gscan, dim3(B, 32), dim3(64), 0, stream, Hc, HS);
    hipLaunchKernelGGL(fb_out, dim3(NCH), dim3(256), 0, stream, qb, alg, vbT, HS, out);
  }
}

// Round 9
// 59.036 us; speedup vs baseline: 2.3931x; 2.3931x over previous
//
#include <hip/hip_runtime.h>
#include <math.h>

// Retention via chunked linear attention — 5-kernel pipeline, 512-thread mid/out.
//   Q' = (xq@W)*gamma^{-n}/sqrt(D);  K'' = (xk@W)*gamma^m/sqrt(rowsum[m]);  V = xv@W
//   A_c = tril(Q'_c K''_c^T) (bf16, global al)
//   s[n] = rowsum(A_c)[n] + Q'_n . csp_c   (csp = f32 prefix of chunk col-sums)
//   V'_m = V_m / max(|s_m|,1)
//   Hc = (K''^T V')^T per chunk;  HS = exclusive chunk prefix (f32 accum, bf16)
//   out = Q'@SE + A@V'
// Occupancy design: proj = 768 blocks (3/CU, 12 w/CU); mid/out = 256 blocks x 512
// threads (8 w/CU = 2 w/SIMD) — fixes the 1-wave/SIMD latency exposure.

constexpr int B = 8, S = 2048, D = 128;
constexpr int C = 64, NC = S / C;
constexpr int BS = B * S;
constexpr int NCH = B * NC;            // 256 chunks
#define GAMMA_F 0.9865f

typedef __attribute__((ext_vector_type(8))) short short8;
typedef __attribute__((ext_vector_type(8))) unsigned short ushort8;
typedef __attribute__((ext_vector_type(4))) float f32x4;

__device__ inline unsigned short f2bf(float f) {
  unsigned u = __builtin_bit_cast(unsigned, f);
  return (unsigned short)((u + 0x7FFF + ((u >> 16) & 1)) >> 16);   // RNE
}
__device__ inline float bf2f(unsigned short h) {
  return __builtin_bit_cast(float, (unsigned)h << 16);
}

// ---------------- K0: wt = W^T bf16 + decay scalars (f64 closed form) ----------
__global__ void k_init(const float* __restrict__ W, unsigned short* __restrict__ wt,
                       float* __restrict__ qs, float* __restrict__ ks) {
  int bid = blockIdx.x, tid = threadIdx.x;
  if (bid < 64) {
    int idx = bid * 256 + tid;
    int k = idx & 127, c = idx >> 7;
    wt[c * 128 + k] = f2bf(W[k * 128 + c]);
  } else {
    int n = (bid - 64) * 256 + tid;
    if (n < S) {
      double g = (double)GAMMA_F;
      double lg = log(g);
      double gmn = exp(-lg * (double)n);
      double gn  = exp(lg * (double)n);
      double ginv = 1.0 / g;
      double rs = (exp(log(ginv) * (double)(n + 1)) - 1.0) / (ginv - 1.0);
      qs[n] = (float)(gmn / sqrt(128.0));
      ks[n] = (float)(gn / sqrt(rs));
    }
  }
}

// ---------------- K1: projections via MFMA, bf16 out; fused chunk col-sums ------
// grid (NCH, 3), block 256.
__global__ __launch_bounds__(256) void k_proj(
    const float* __restrict__ xq, const float* __restrict__ xk,
    const float* __restrict__ xv, const unsigned short* __restrict__ wt,
    const float* __restrict__ qs, const float* __restrict__ ks,
    unsigned short* __restrict__ qb, unsigned short* __restrict__ kb,
    unsigned short* __restrict__ vb, float* __restrict__ cs) {
  __shared__ float css[4][128];
  int mat = blockIdx.y;
  const float* X = (mat == 0) ? xq : ((mat == 1) ? xk : xv);
  unsigned short* Ob = (mat == 0) ? qb : ((mat == 1) ? kb : vb);

  int tid = threadIdx.x, w = tid >> 6, lane = tid & 63;
  int bc = blockIdx.x;
  int r0 = bc * 64 + w * 16;
  int arow = r0 + (lane & 15);
  int kg = (lane >> 4) * 8;

  f32x4 acc[8];
#pragma unroll
  for (int j = 0; j < 8; j++) acc[j] = (f32x4){0.f, 0.f, 0.f, 0.f};
#pragma unroll
  for (int t = 0; t < 4; t++) {
    int k0 = t * 32 + kg;
    const float* ap = X + (size_t)arow * 128 + k0;
    float a8[8];
    *(f32x4*)(a8) = *(const f32x4*)ap;
    *(f32x4*)(a8 + 4) = *(const f32x4*)(ap + 4);
    short8 af;
#pragma unroll
    for (int i = 0; i < 8; i++) af[i] = (short)f2bf(a8[i]);
#pragma unroll
    for (int j = 0; j < 8; j++) {
      short8 bf = *(const short8*)(wt + (size_t)(j * 16 + (lane & 15)) * 128 + k0);
      acc[j] = __builtin_amdgcn_mfma_f32_16x16x32_bf16(af, bf, acc[j], 0, 0, 0);
    }
  }
  int crow = r0 + (lane >> 4) * 4;
  float csp[8];
#pragma unroll
  for (int j = 0; j < 8; j++) csp[j] = 0.f;
#pragma unroll
  for (int rr = 0; rr < 4; rr++) {
    int row = crow + rr;
    int n = row & (S - 1);
    float sc = (mat == 0) ? qs[n] : ((mat == 1) ? ks[n] : 1.0f);
#pragma unroll
    for (int j = 0; j < 8; j++) {
      float v = acc[j][rr] * sc;
      Ob[(size_t)row * 128 + j * 16 + (lane & 15)] = f2bf(v);
      csp[j] += v;
    }
  }
  if (mat == 1) {
#pragma unroll
    for (int j = 0; j < 8; j++) {
      csp[j] += __shfl_xor(csp[j], 16);
      csp[j] += __shfl_xor(csp[j], 32);
    }
    if ((lane >> 4) == 0)
#pragma unroll
      for (int j = 0; j < 8; j++) css[w][j * 16 + lane] = csp[j];
  }
  __syncthreads();
  if (mat == 1 && tid < 128)
    cs[bc * 128 + tid] = css[0][tid] + css[1][tid] + css[2][tid] + css[3][tid];
}

// ---------------- K2: A-tile + s + V' + transposes + Hc (512 threads) ----------
// grid NCH, block 512 (8 waves).
__global__ __launch_bounds__(512) void k_mid(
    const unsigned short* __restrict__ qb, const unsigned short* __restrict__ kb,
    const unsigned short* __restrict__ vb, const float* __restrict__ cs,
    unsigned short* __restrict__ al, unsigned short* __restrict__ vbT,
    unsigned short* __restrict__ Hc) {
  __shared__ unsigned short kraw[64][136];  // 17.4 KB staging
  __shared__ unsigned short kT[128][72];    // 18.4 KB K''^T (m-fast)
  __shared__ unsigned short vT[128][72];    // 18.4 KB V'^T
  __shared__ float csp[128];
  __shared__ float invl[64];
  __shared__ float rsum_l[2][64];
  int bc = blockIdx.x, b = bc >> 5, c = bc & 31;
  int tid = threadIdx.x, w = tid >> 6, lane = tid & 63;
  int l15 = lane & 15;
  int kg = (lane >> 4) * 8;
  size_t base = (size_t)bc * C * D;

  // csp[d] = f32 prefix of prior-chunk col sums (independent loads)
  if (tid < 128) {
    float a = 0.f;
    for (int cc = 0; cc < c; cc++) a += cs[(size_t)(b * NC + cc) * 128 + tid];
    csp[tid] = a;
  }

  // Phase A: A = tril(Q'K''^T). Wave w: row-tile rt = w&3, mt pair mh = w>>2.
  {
    int rt = w & 3, mh = w >> 2;
    int arow = rt * 16 + l15;
    int crow = rt * 16 + (lane >> 4) * 4;
    f32x4 a1[2];
#pragma unroll
    for (int mi = 0; mi < 2; mi++) a1[mi] = (f32x4){0.f, 0.f, 0.f, 0.f};
#pragma unroll
    for (int t = 0; t < 4; t++) {
      int k0 = t * 32 + kg;
      short8 af = *(const short8*)(qb + base + (size_t)arow * D + k0);
#pragma unroll
      for (int mi = 0; mi < 2; mi++) {
        int mt = mh * 2 + mi;
        short8 bf = *(const short8*)(kb + base + (size_t)(mt * 16 + l15) * D + k0);
        a1[mi] = __builtin_amdgcn_mfma_f32_16x16x32_bf16(af, bf, a1[mi], 0, 0, 0);
      }
    }
    unsigned short* alg = al + (size_t)bc * 64 * 64;
    float rsp[4] = {0.f, 0.f, 0.f, 0.f};
#pragma unroll
    for (int mi = 0; mi < 2; mi++)
#pragma unroll
      for (int rr = 0; rr < 4; rr++) {
        int n_l = crow + rr, m_l = (mh * 2 + mi) * 16 + l15;
        float mv = (n_l >= m_l) ? a1[mi][rr] : 0.f;
        alg[n_l * 64 + m_l] = f2bf(mv);
        rsp[rr] += mv;
      }
#pragma unroll
    for (int rr = 0; rr < 4; rr++) {
      float r = rsp[rr];
      r += __shfl_xor(r, 1); r += __shfl_xor(r, 2);
      r += __shfl_xor(r, 4); r += __shfl_xor(r, 8);
      if (l15 == 0) rsum_l[mh][crow + rr] = r;
    }
  }
  // Phase C: stage K chunk into kraw (independent of A/B)
#pragma unroll
  for (int i = 0; i < 2; i++) {
    int e = (i * 512 + tid) * 8;
    *(ushort8*)&kraw[e >> 7][e & 127] = *(const ushort8*)(kb + base + e);
  }
  __syncthreads();   // csp, rsum_l, kraw visible

  // Phase B: s = rowsum(A) + Q'.csp; invl. 8 threads per row.
  {
    int row = tid >> 3, part = tid & 7;
    const unsigned short* q = qb + base + (size_t)row * D + part * 16;
    ushort8 q8a = *(const ushort8*)q;
    ushort8 q8b = *(const ushort8*)(q + 8);
    float dot = 0.f;
#pragma unroll
    for (int ii = 0; ii < 8; ii++) {
      dot = fmaf(bf2f(q8a[ii]), csp[part * 16 + ii], dot);
      dot = fmaf(bf2f(q8b[ii]), csp[part * 16 + 8 + ii], dot);
    }
    dot += __shfl_xor(dot, 1); dot += __shfl_xor(dot, 2); dot += __shfl_xor(dot, 4);
    if (part == 0) {
      float s = rsum_l[0][row] + rsum_l[1][row] + dot;
      invl[row] = 1.f / fmaxf(fabsf(s), 1.f);
    }
  }
  // Phase D: kT pack (conflict-light column gathers)
  {
    int d = tid & 127, mh2 = tid >> 7;   // 0..3
#pragma unroll
    for (int mg = 0; mg < 2; mg++) {
      ushort8 pk;
#pragma unroll
      for (int i = 0; i < 8; i++) pk[i] = kraw[mh2 * 16 + mg * 8 + i][d];
      *(ushort8*)&kT[d][mh2 * 16 + mg * 8] = pk;
    }
  }
  __syncthreads();   // invl, kT visible; kraw free
  // Phase E: V' = V * invl -> kraw
#pragma unroll
  for (int i = 0; i < 2; i++) {
    int e = (i * 512 + tid) * 8;
    int row = e >> 7, col = e & 127;
    ushort8 v8 = *(const ushort8*)(vb + base + e);
    float inv = invl[row];
    ushort8 o;
#pragma unroll
    for (int ii = 0; ii < 8; ii++) o[ii] = f2bf(bf2f(v8[ii]) * inv);
    *(ushort8*)&kraw[row][col] = o;
  }
  __syncthreads();
  // Phase F: vT pack
  {
    int d = tid & 127, mh2 = tid >> 7;
#pragma unroll
    for (int mg = 0; mg < 2; mg++) {
      ushort8 pk;
#pragma unroll
      for (int i = 0; i < 8; i++) pk[i] = kraw[mh2 * 16 + mg * 8 + i][d];
      *(ushort8*)&vT[d][mh2 * 16 + mg * 8] = pk;
    }
  }
  __syncthreads();
  // Phase G: Hc[d2][d1] = sum_m V'[m][d2] K''[m][d1]. Wave w: d2 tile w.
  {
    f32x4 hacc[8];
#pragma unroll
    for (int j = 0; j < 8; j++) hacc[j] = (f32x4){0.f, 0.f, 0.f, 0.f};
#pragma unroll
    for (int t = 0; t < 2; t++) {
      int k0 = t * 32 + kg;
      short8 a2 = *(const short8*)&vT[w * 16 + l15][k0];
#pragma unroll
      for (int j = 0; j < 8; j++) {
        short8 bf = *(const short8*)&kT[j * 16 + l15][k0];
        hacc[j] = __builtin_amdgcn_mfma_f32_16x16x32_bf16(a2, bf, hacc[j], 0, 0, 0);
      }
    }
    unsigned short* g = Hc + (size_t)bc * D * D;
#pragma unroll
    for (int j = 0; j < 8; j++)
#pragma unroll
      for (int rr = 0; rr < 4; rr++)
        g[(size_t)(w * 16 + (lane >> 4) * 4 + rr) * D + j * 16 + l15] =
            f2bf(hacc[j][rr]);
  }
  // vbT -> global
  {
    int d = tid >> 2, pp = (tid & 3) * 16;
    unsigned short* dst = vbT + (size_t)bc * D * C + (size_t)d * C + pp;
    *(ushort8*)(dst) = *(ushort8*)&vT[d][pp];
    *(ushort8*)(dst + 8) = *(ushort8*)&vT[d][pp + 8];
  }
}

// ---------------- K3: HS = exclusive chunk prefix of Hc (vectorized) -----------
__global__ __launch_bounds__(64) void k_gscan(const unsigned short* __restrict__ Hc,
                                              unsigned short* __restrict__ HS) {
  int b = blockIdx.x, gy = blockIdx.y, t = threadIdx.x;
  int d2 = gy * 4 + (t >> 4), d1 = (t & 15) * 8;
  size_t off = ((size_t)(b * NC) * D + d2) * D + d1;
  ushort8 v[NC];
#pragma unroll
  for (int c = 0; c < NC; c++)
    v[c] = *(const ushort8*)(Hc + off + (size_t)c * D * D);
  float run[8];
#pragma unroll
  for (int j = 0; j < 8; j++) run[j] = 0.f;
#pragma unroll
  for (int c = 0; c < NC; c++) {
    ushort8 o;
#pragma unroll
    for (int j = 0; j < 8; j++) {
      o[j] = f2bf(run[j]);
      run[j] += bf2f(v[c][j]);
    }
    *(ushort8*)(HS + off + (size_t)c * D * D) = o;
  }
}

// ---------------- K4: out = Q'@SE + A@V' (512 threads, no LDS) ------------------
// grid NCH, block 512. Wave w: row-tile rt = w>>1, col-half ch = w&1.
__global__ __launch_bounds__(512) void k_out(
    const unsigned short* __restrict__ qb, const unsigned short* __restrict__ al,
    const unsigned short* __restrict__ vbT, const unsigned short* __restrict__ HS,
    float* __restrict__ out) {
  int bc = blockIdx.x, tid = threadIdx.x, w = tid >> 6, lane = tid & 63;
  int l15 = lane & 15;
  size_t base = (size_t)bc * C * D;
  int kg = (lane >> 4) * 8;
  int rt = w >> 1, ch = w & 1;
  int arow = rt * 16 + l15;
  int crow = rt * 16 + (lane >> 4) * 4;

  f32x4 acc[4];
#pragma unroll
  for (int j = 0; j < 4; j++) acc[j] = (f32x4){0.f, 0.f, 0.f, 0.f};
  const unsigned short* hrow = HS + (size_t)bc * D * D;
#pragma unroll
  for (int t = 0; t < 4; t++) {
    int k0 = t * 32 + kg;
    short8 af = *(const short8*)(qb + base + (size_t)arow * D + k0);
#pragma unroll
    for (int jj = 0; jj < 4; jj++) {
      int j = ch * 4 + jj;
      short8 bf = *(const short8*)(hrow + (size_t)(j * 16 + l15) * D + k0);
      acc[jj] = __builtin_amdgcn_mfma_f32_16x16x32_bf16(af, bf, acc[jj], 0, 0, 0);
    }
  }
  const unsigned short* alg = al + (size_t)bc * 64 * 64;
  const unsigned short* vt = vbT + (size_t)bc * D * C;
#pragma unroll
  for (int t = 0; t < 2; t++) {
    int k0 = t * 32 + kg;
    short8 af = *(const short8*)(alg + (size_t)arow * 64 + k0);
#pragma unroll
    for (int jj = 0; jj < 4; jj++) {
      int j = ch * 4 + jj;
      short8 bf = *(const short8*)(vt + (size_t)(j * 16 + l15) * C + k0);
      acc[jj] = __builtin_amdgcn_mfma_f32_16x16x32_bf16(af, bf, acc[jj], 0, 0, 0);
    }
  }
#pragma unroll
  for (int jj = 0; jj < 4; jj++)
#pragma unroll
    for (int rr = 0; rr < 4; rr++)
      out[base + (size_t)(crow + rr) * D + (ch * 4 + jj) * 16 + l15] = acc[jj][rr];
}

extern "C" void kernel_launch(void* const* d_in, const int* in_sizes, int n_in,
                              void* d_out, int out_size, void* d_ws, size_t ws_size,
                              hipStream_t stream) {
  const float* xq = (const float*)d_in[0];
  const float* xk = (const float*)d_in[1];
  const float* xv = (const float*)d_in[2];
  const float* W  = (const float*)d_in[3];
  float* out = (float*)d_out;

  char* p = (char*)d_ws;
  unsigned short* qb  = (unsigned short*)p;  p += (size_t)BS * D * 2;
  unsigned short* kb  = (unsigned short*)p;  p += (size_t)BS * D * 2;
  unsigned short* vb  = (unsigned short*)p;  p += (size_t)BS * D * 2;
  unsigned short* vbT = (unsigned short*)p;  p += (size_t)NCH * D * C * 2;
  unsigned short* al  = (unsigned short*)p;  p += (size_t)NCH * C * C * 2;
  unsigned short* Hc  = (unsigned short*)p;  p += (size_t)NCH * D * D * 2;
  unsigned short* HS  = (unsigned short*)p;  p += (size_t)NCH * D * D * 2;
  unsigned short* wt  = (unsigned short*)p;  p += (size_t)D * D * 2;
  float* cs = (float*)p;                     p += (size_t)NCH * D * 4;
  float* qs = (float*)p;                     p += (size_t)S * 4;
  float* ks = (float*)p;                     p += (size_t)S * 4;

  hipLaunchKernelGGL(k_init, dim3(72), dim3(256), 0, stream, W, wt, qs, ks);
  hipLaunchKernelGGL(k_proj, dim3(NCH, 3), dim3(256), 0, stream,
                     xq, xk, xv, wt, qs, ks, qb, kb, vb, cs);
  hipLaunchKernelGGL(k_mid, dim3(NCH), dim3(512), 0, stream, qb, kb, vb, cs,
                     al, vbT, Hc);
  hipLaunchKernelGGL(k_gscan, dim3(B, 32), dim3(64), 0, stream, Hc, HS);
  hipLaunchKernelGGL(k_out, dim3(NCH), dim3(512), 0, stream, qb, al, vbT, HS, out);
}